// Round 13
// baseline (166.425 us; speedup 1.0000x reference)
//
#include <hip/hip_runtime.h>
#include <hip/hip_bf16.h>
#include <stdint.h>

#define B_  8
#define T_  2048
#define E_  512

typedef __attribute__((ext_vector_type(8))) __bf16 bf16x8;
typedef __attribute__((ext_vector_type(8))) unsigned short ushort8;
typedef __attribute__((ext_vector_type(4))) unsigned short ushort4v;
typedef __attribute__((ext_vector_type(16))) float f32x16;

__device__ __forceinline__ float bf2f(unsigned short u) {
  union { unsigned int u; float f; } c; c.u = ((unsigned int)u) << 16; return c.f;
}
__device__ __forceinline__ unsigned short f2bf(float f) {
  union { float f; unsigned int u; } c; c.f = f;
  unsigned int u = c.u;
  unsigned int r = (u + 0x7FFFu + ((u >> 16) & 1u)) >> 16;
  return (unsigned short)r;
}

__device__ __forceinline__ void gload_lds16(const void* g, void* l) {
  __builtin_amdgcn_global_load_lds(
      (const __attribute__((address_space(1))) uint32_t*)g,
      (__attribute__((address_space(3))) uint32_t*)l, 16, 0, 0);
}

// ---------------- fused bf16-convert + transpose ----------------
__global__ __launch_bounds__(256)
void trans_conv_kernel(const float* __restrict__ x, unsigned short* __restrict__ xbf,
                       unsigned short* __restrict__ xT) {
  __shared__ unsigned short tile[64][66];
  const int t0 = blockIdx.x * 64, e0 = blockIdx.y * 64, b = blockIdx.z;
  const int tid = threadIdx.x;
  const float* xb = x + ((size_t)b * T_ + t0) * E_ + e0;
  unsigned short* xbf_b = xbf + ((size_t)b * T_ + t0) * E_ + e0;
#pragma unroll
  for (int it = 0; it < 4; ++it) {
    int tr = (tid >> 4) + it * 16;
    int ec = (tid & 15) * 4;
    float4 f = *reinterpret_cast<const float4*>(xb + (size_t)tr * E_ + ec);
    ushort4v o;
    o[0] = f2bf(f.x); o[1] = f2bf(f.y); o[2] = f2bf(f.z); o[3] = f2bf(f.w);
    *reinterpret_cast<ushort4v*>(xbf_b + (size_t)tr * E_ + ec) = o;
    tile[ec + 0][tr] = o[0];
    tile[ec + 1][tr] = o[1];
    tile[ec + 2][tr] = o[2];
    tile[ec + 3][tr] = o[3];
  }
  __syncthreads();
  unsigned short* dst = xT + ((size_t)b * E_ + e0) * T_ + t0;
#pragma unroll
  for (int it = 0; it < 2; ++it) {
    int er = (tid >> 3) + it * 32;
    int tg = (tid & 7) * 8;
    ushort8 r;
#pragma unroll
    for (int j = 0; j < 8; ++j) r[j] = tile[er][tg + j];
    *reinterpret_cast<ushort8*>(dst + (size_t)er * T_ + tg) = r;
  }
}

// WT[n][kk] = (n<512 ? Wq[kk][n]*scale : Wk[kk][n-512]);  bqk[n] fused bias
__global__ __launch_bounds__(256)
void conv_w_kernel(const float* __restrict__ Wq, const float* __restrict__ Wk,
                   const float* __restrict__ bq, const float* __restrict__ bk,
                   unsigned short* __restrict__ WT, float* __restrict__ bqk, float scale) {
  int idx = blockIdx.x * 256 + threadIdx.x;
  int n  = idx >> 9;
  int kk = idx & 511;
  float v = (n < E_) ? Wq[kk * E_ + n] * scale : Wk[kk * E_ + (n - E_)];
  WT[idx] = f2bf(v);
  if (idx < 2 * E_) {
    float bv = (idx < E_) ? bq[idx] * scale : bk[idx - E_];
    bqk[idx] = bv;
  }
}

// ====== 128x128 GEMM, r12 rotation schedule, 32x32x16 MFMA ======
// 4 waves (2M x 2N), per-wave 64x64 = 2x2 tiles of 32x32 (acc = 2x2 f32x16 = 64
// regs, spill-safe). BK=64. LDS 80 KiB: A bufs 3x8192 shorts, B bufs 2x8192.
// Rotation/sync identical to the PASSING r12 gemm1b (1 barrier/K-tile,
// vmcnt(4) counted). Fragment mapping (32x32x16): A/B lane = row(lane&31),
// k = (lane>>5)*8 + e; C/D col = lane&31, row = (reg&3)+8*(reg>>2)+4*(lane>>5).
// OUT: 0 = bf16 +bias; 1 = bf16 exp + partial rowsum R; 2 = f32 * (1/rowsum),
// rowsum folded in from R (16 partials).
#define STG_A1(abuf_, kt) do {                                                  \
  _Pragma("unroll") for (int r_ = 0; r_ < 4; ++r_)                              \
    gload_lds16(gA + (long long)(r_ * 32) * lda + (long long)(kt) * 64,         \
                &sm[(abuf_) * 8192 + r_ * 2048 + tid * 8]);                     \
} while (0)

#define STG_B1(bbuf_, kt) do {                                                  \
  _Pragma("unroll") for (int r_ = 0; r_ < 4; ++r_)                              \
    gload_lds16(gB + (long long)(r_ * 32) * ldb + (long long)(kt) * 64,         \
                &sm[24576 + (bbuf_) * 8192 + r_ * 2048 + tid * 8]);             \
} while (0)

template<int OUT>
__global__ __launch_bounds__(256)
void gemm32(const unsigned short* __restrict__ A, int lda, long long strA,
            const unsigned short* __restrict__ B, int ldb, long long strB,
            void* __restrict__ Cv, int ldc, long long strC,
            int K, const float* __restrict__ bias, int NBX, int NBY,
            float* __restrict__ Rg)
{
  __shared__ unsigned short sm[40960];   // 80 KiB -> 2 blocks/CU
  const int tid  = threadIdx.x;
  const int lane = tid & 63;
  const int wv   = tid >> 6;
  const int wrp  = wv >> 1;
  const int wcp  = wv & 1;
  const int l31  = lane & 31;
  const int h8   = (lane >> 5) * 8;
  const int h4   = (lane >> 5) * 4;
  const int xorc = (lane & 7) << 3;

  const int nwg = gridDim.x, bid = blockIdx.x;
  const int qq = nwg >> 3, rr = nwg & 7, xc = bid & 7, ii = bid >> 3;
  const int wg = (xc < rr ? xc * (qq + 1) : rr * (qq + 1) + (xc - rr) * qq) + ii;
  const int bx = wg % NBX;
  const int tt = wg / NBX;
  const int by = tt % NBY;
  const int bz = tt / NBY;

  const long long m0 = (long long)by * 128;
  const long long n0 = (long long)bx * 128;
  const unsigned short* Ab = A + (long long)bz * strA + m0 * lda;
  const unsigned short* Bb = B + (long long)bz * strB + n0 * ldb;

  const int srow = tid >> 3;                                   // 0..31
  const int scol = ((tid & 7) * 8) ^ ((srow & 7) << 3);
  const unsigned short* gA = Ab + (long long)srow * lda + scol;
  const unsigned short* gB = Bb + (long long)srow * ldb + scol;

  const int aBase = (wrp * 64 + l31) * 64;
  const int bBase = (wcp * 64 + l31) * 64;

  f32x16 acc[2][2];
#pragma unroll
  for (int i = 0; i < 2; ++i)
#pragma unroll
    for (int j = 0; j < 2; ++j)
#pragma unroll
      for (int e = 0; e < 16; ++e) acc[i][j][e] = 0.f;

  bf16x8 aA[2][4], bBv[2][4];
  const int NT = K >> 6;   // >= 8 for all uses

  // prologue: A(0)->abuf0, B(0)->bbuf0, A(1)->abuf1; vmcnt(4) retires tile 0.
  STG_A1(0, 0);
  STG_B1(0, 0);
  STG_A1(1, 1);
  asm volatile("s_waitcnt vmcnt(4)" ::: "memory");
  __builtin_amdgcn_s_barrier();

  int ab = 0;   // t % 3
  int bb = 0;   // t % 2
  for (int t = 0; t < NT; ++t) {
    if (t + 1 < NT) STG_B1(bb ^ 1, t + 1);
    if (t + 2 < NT) { int ab2 = ab + 2; if (ab2 >= 3) ab2 -= 3; STG_A1(ab2, t + 2); }
    const int pbA = ab * 8192;
    const int pbB = 24576 + bb * 8192;
#pragma unroll
    for (int mt = 0; mt < 2; ++mt)
#pragma unroll
      for (int ks = 0; ks < 4; ++ks)
        aA[mt][ks] = *reinterpret_cast<const bf16x8*>(
            &sm[pbA + aBase + mt * 2048 + ((ks * 16 + h8) ^ xorc)]);
#pragma unroll
    for (int nt = 0; nt < 2; ++nt)
#pragma unroll
      for (int ks = 0; ks < 4; ++ks)
        bBv[nt][ks] = *reinterpret_cast<const bf16x8*>(
            &sm[pbB + bBase + nt * 2048 + ((ks * 16 + h8) ^ xorc)]);
    __builtin_amdgcn_s_setprio(1);
#pragma unroll
    for (int mt = 0; mt < 2; ++mt)
#pragma unroll
      for (int nt = 0; nt < 2; ++nt)
#pragma unroll
        for (int ks = 0; ks < 4; ++ks)
          acc[mt][nt] = __builtin_amdgcn_mfma_f32_32x32x16_bf16(
              aA[mt][ks], bBv[nt][ks], acc[mt][nt], 0, 0, 0);
    __builtin_amdgcn_s_setprio(0);
    if (t + 2 < NT)      asm volatile("s_waitcnt vmcnt(4)" ::: "memory");
    else                 asm volatile("s_waitcnt vmcnt(0)" ::: "memory");
    __builtin_amdgcn_s_barrier();
    ab = (ab == 2) ? 0 : ab + 1;
    bb ^= 1;
  }

  // ---- epilogue ----
  if (OUT == 2) {
    // fold rowsum: 1/sum of 16 partials for this block's 128 rows
    float* rsum = (float*)sm;
    if (tid < 128) {
      float s = 0.f;
#pragma unroll
      for (int c = 0; c < 16; ++c)
        s += Rg[((long long)(bz * 16 + c)) * 2048 + m0 + tid];
      rsum[tid] = 1.0f / s;
    }
    __syncthreads();
    float* Cb = (float*)Cv + (long long)bz * strC;
#pragma unroll
    for (int mt = 0; mt < 2; ++mt)
#pragma unroll
      for (int reg = 0; reg < 16; ++reg) {
        const int lrow = wrp * 64 + mt * 32 + (reg & 3) + 8 * (reg >> 2) + h4;
        const float inv = rsum[lrow];
        const long long row = m0 + lrow;
#pragma unroll
        for (int nt = 0; nt < 2; ++nt)
          Cb[row * ldc + n0 + wcp * 64 + nt * 32 + l31] = acc[mt][nt][reg] * inv;
      }
    return;
  }
  if (OUT == 1) {
#pragma unroll
    for (int mt = 0; mt < 2; ++mt)
#pragma unroll
      for (int nt = 0; nt < 2; ++nt)
#pragma unroll
        for (int reg = 0; reg < 16; ++reg) acc[mt][nt][reg] = __expf(acc[mt][nt][reg]);
    float* rps = (float*)(sm + 17664);   // 256 f32, past the 128x136 C-stage
#pragma unroll
    for (int mt = 0; mt < 2; ++mt)
#pragma unroll
      for (int reg = 0; reg < 16; ++reg) {
        float s = acc[mt][0][reg] + acc[mt][1][reg];
        s += __shfl_xor(s, 1); s += __shfl_xor(s, 2);
        s += __shfl_xor(s, 4); s += __shfl_xor(s, 8); s += __shfl_xor(s, 16);
        if (l31 == 0) {
          const int lrow = wrp * 64 + mt * 32 + (reg & 3) + 8 * (reg >> 2) + h4;
          rps[wcp * 128 + lrow] = s;
        }
      }
  } else if (bias) {
    float bv[2];
#pragma unroll
    for (int nt = 0; nt < 2; ++nt) bv[nt] = bias[n0 + wcp * 64 + nt * 32 + l31];
#pragma unroll
    for (int mt = 0; mt < 2; ++mt)
#pragma unroll
      for (int nt = 0; nt < 2; ++nt)
#pragma unroll
        for (int reg = 0; reg < 16; ++reg) acc[mt][nt][reg] += bv[nt];
  }
  // C-stage into LDS (136-short padded rows), coalesced ushort8 stores
#pragma unroll
  for (int mt = 0; mt < 2; ++mt)
#pragma unroll
    for (int reg = 0; reg < 16; ++reg) {
      const int lrow = wrp * 64 + mt * 32 + (reg & 3) + 8 * (reg >> 2) + h4;
#pragma unroll
      for (int nt = 0; nt < 2; ++nt)
        sm[lrow * 136 + wcp * 64 + nt * 32 + l31] = f2bf(acc[mt][nt][reg]);
    }
  __syncthreads();
  if (OUT == 1) {
    float* rps = (float*)(sm + 17664);
    if (tid < 128) {
      const float s = rps[tid] + rps[128 + tid];
      Rg[((long long)bz * NBX + bx) * 2048 + m0 + tid] = s;
    }
  }
  unsigned short* C = (unsigned short*)Cv + (long long)bz * strC;
#pragma unroll
  for (int it = 0; it < 8; ++it) {
    const int row = it * 16 + (tid >> 4);
    const int chunk = tid & 15;
    ushort8 v = *reinterpret_cast<const ushort8*>(&sm[row * 136 + chunk * 8]);
    *reinterpret_cast<ushort8*>(&C[(m0 + row) * ldc + n0 + chunk * 8]) = v;
  }
}

// ---------------- launch ----------------
extern "C" void kernel_launch(void* const* d_in, const int* in_sizes, int n_in,
                              void* d_out, int out_size, void* d_ws, size_t ws_size,
                              hipStream_t stream)
{
  const float* x  = (const float*)d_in[0];
  const float* Wq = (const float*)d_in[1];
  const float* bq = (const float*)d_in[2];
  const float* Wk = (const float*)d_in[3];
  const float* bk = (const float*)d_in[4];
  float* out = (float*)d_out;

  char* w = (char*)d_ws;
  unsigned short* xbf  = (unsigned short*)w;  w += (size_t)B_ * T_ * E_ * 2;
  unsigned short* xT   = (unsigned short*)w;  w += (size_t)B_ * T_ * E_ * 2;
  unsigned short* WT   = (unsigned short*)w;  w += (size_t)2 * E_ * E_ * 2;
  float*          bqk  = (float*)w;           w += (size_t)2 * E_ * 4;
  float*          R    = (float*)w;           w += (size_t)B_ * 16 * T_ * 4;     // 2 MB
  unsigned short* qk   = (unsigned short*)w;  w += (size_t)B_ * T_ * 2 * E_ * 2;
  unsigned short* attn = (unsigned short*)w;  w += (size_t)B_ * T_ * T_ * 2;

  const float scale = 0.044194173824159216f;  // 512^-0.5

  trans_conv_kernel<<<dim3(32, 8, 8), 256, 0, stream>>>(x, xbf, xT);
  conv_w_kernel<<<2048, 256, 0, stream>>>(Wq, Wk, bq, bk, WT, bqk, scale);

  // qk[16384, 1024] = xbf @ WT^T (+bias)   grid 8x128 = 1024 blocks
  gemm32<0><<<1024, 256, 0, stream>>>(
      xbf, E_, 0, WT, E_, 0, qk, 2 * E_, 0, E_, bqk, 8, 128, nullptr);

  // P[b][2048,2048] = exp(q_b @ k_b^T) + partial rowsums   grid 16x16x8 = 2048
  gemm32<1><<<2048, 256, 0, stream>>>(
      qk, 2 * E_, (long long)T_ * 2 * E_,
      qk + E_, 2 * E_, (long long)T_ * 2 * E_,
      attn, T_, (long long)T_ * T_, E_, nullptr, 16, 16, R);

  // out[b][2048,512] = (P_b @ x_b) / rowsum  (rowsum folded from R)   grid 512
  gemm32<2><<<512, 256, 0, stream>>>(
      attn, T_, (long long)T_ * T_,
      xT, T_, (long long)E_ * T_,
      out, E_, (long long)T_ * E_, T_, nullptr, 4, 16, R);
}